// Round 2
// baseline (674.778 us; speedup 1.0000x reference)
//
#include <hip/hip_runtime.h>

#define NW    16
#define NEUR  128
#define NPTS  65536
#define SIGMA 0.02f
#define U_MEAN 0.0f
#define U_SD   1.0f

#define TILE   128          // points per block
#define NTHR   512          // 8 waves
#define HPAD   132          // row stride in halves: 264B = 66 banks === 2 mod 8 -> conflict-free q-groups
#define WMAT_HALVES (NEUR*HPAD)           // 16896 halves = 33792 B per weight matrix (2112 float4)
#define WT_TOTAL (2*NW*WMAT_HALVES)       // 540672 halves = 1,081,344 B in d_ws

typedef _Float16 half8 __attribute__((ext_vector_type(8)));
typedef float    f32x4 __attribute__((ext_vector_type(4)));

__device__ __forceinline__ float tanh_fast(float x) {
    // tanh(x) = 1 - 2/(1+exp(2x)); exp->inf / ->0 saturate correctly to +-1
    float e = __expf(2.0f * x);
    return 1.0f - 2.0f * __builtin_amdgcn_rcpf(1.0f + e);
}

// W_hid fp32 [l][w][d][e]  ->  wt fp16 [(l*NW+w)][e][HPAD]  (transposed: k=d contiguous, padded)
__global__ void prep_kernel(const float* __restrict__ W_hid, _Float16* __restrict__ wt) {
    int idx  = blockIdx.x * 256 + threadIdx.x;     // grid sized exactly: 2112*256 = 540672
    int d    = idx % HPAD;
    int rest = idx / HPAD;
    int e    = rest & (NEUR - 1);
    int lw   = rest >> 7;
    _Float16 v = (_Float16)0.0f;
    if (d < NEUR) v = (_Float16)W_hid[(lw * NEUR + d) * NEUR + e];
    wt[idx] = v;
}

// acc[c] = 16x16 tile c of Hlds[128rows x 128k] @ Wlds[128n x 128k]^T
__device__ __forceinline__ void gemm_tile(const _Float16* Hbase, const _Float16* Wbase,
                                          int row0, int m, int q, f32x4 acc[8]) {
    const f32x4 z = {0.f, 0.f, 0.f, 0.f};
#pragma unroll
    for (int c = 0; c < 8; ++c) acc[c] = z;
#pragma unroll
    for (int s = 0; s < 4; ++s) {
        half8 a = *(const half8*)(Hbase + (row0 + m) * HPAD + s * 32 + q * 8);
#pragma unroll
        for (int c = 0; c < 8; ++c) {
            half8 b = *(const half8*)(Wbase + (c * 16 + m) * HPAD + s * 32 + q * 8);
            acc[c] = __builtin_amdgcn_mfma_f32_16x16x32_f16(a, b, acc[c], 0, 0, 0);
        }
    }
}

__device__ __forceinline__ void act_store(_Float16* Hbase, const float* __restrict__ bias,
                                          int row0, int m, int q, const f32x4 acc[8]) {
#pragma unroll
    for (int c = 0; c < 8; ++c) {
        float b = bias[c * 16 + m];
#pragma unroll
        for (int r = 0; r < 4; ++r) {
            // C/D layout: col = lane&15 (=m), row = q*4 + r ; conflict-free with HPAD=132
            Hbase[(row0 + q * 4 + r) * HPAD + c * 16 + m] = (_Float16)tanh_fast(acc[c][r] + b);
        }
    }
}

__device__ __forceinline__ void stage_w(const float4* __restrict__ g, float4* l4, int t) {
    // 2112 float4 per matrix: 4 per thread + 64-thread tail
    float4 r0 = g[t], r1 = g[t + 512], r2 = g[t + 1024], r3 = g[t + 1536];
    float4 r4;
    if (t < 64) r4 = g[t + 2048];
    l4[t] = r0; l4[t + 512] = r1; l4[t + 1024] = r2; l4[t + 1536] = r3;
    if (t < 64) l4[t + 2048] = r4;
}

__global__ __launch_bounds__(NTHR, 4) void fbpinn_kernel(
    const float* __restrict__ x,     const float* __restrict__ means,
    const float* __restrict__ stds,  const float* __restrict__ mids,
    const float* __restrict__ W_in,  const float* __restrict__ b_in,
    const float* __restrict__ b_hid, const float* __restrict__ W_out,
    const float* __restrict__ b_out, const _Float16* __restrict__ wt,
    float* __restrict__ out)
{
    __shared__ __align__(16) _Float16 Wlds[WMAT_HALVES];   // 33792 B
    __shared__ __align__(16) _Float16 Hlds[TILE * HPAD];   // 33792 B
    __shared__ float xs[TILE];
    __shared__ float wouts[NEUR];

    const int t    = threadIdx.x;
    const int blk  = blockIdx.x;
    const int lane = t & 63;
    const int wave = t >> 6;
    const int m    = lane & 15;        // MFMA col / A-row lane index
    const int q    = lane >> 4;        // MFMA quad
    const int row0 = wave * 16;        // this wave's 16-point slab
    const int p    = t & 127;          // point owned in L0 phase
    const int qq   = t >> 7;           // neuron quarter in L0 phase

    if (t < TILE) xs[t] = x[blk * TILE + t];
    const int   rsel = m & 3;
    float uacc = 0.f;
    f32x4 acc[8];

    for (int w = 0; w < NW; ++w) {
        __syncthreads();   // Hlds/Wlds/wouts free (prev window's GEMM2 + epilogue done)

        // stage W(layer0) + W_out; compute layer 0 (1->128) in fp32, b128 stores
        stage_w((const float4*)(wt + (size_t)(0 * NW + w) * WMAT_HALVES), (float4*)Wlds, t);
        if (t < NEUR) wouts[t] = W_out[w * NEUR + t];

        const float xn = (xs[p] - means[w]) * __builtin_amdgcn_rcpf(stds[w]);
        const float* win = W_in + w * NEUR;
        const float* bin = b_in + w * NEUR;
#pragma unroll
        for (int i8 = 0; i8 < 4; ++i8) {
            half8 hv;
#pragma unroll
            for (int j = 0; j < 8; ++j) {
                int n = qq * 32 + i8 * 8 + j;
                hv[j] = (_Float16)tanh_fast(fmaf(xn, win[n], bin[n]));
            }
            *(half8*)&Hlds[p * HPAD + qq * 32 + i8 * 8] = hv;
        }
        __syncthreads();   // h1, W0, wouts visible

        gemm_tile(Hlds, Wlds, row0, m, q, acc);          // z2 = h1 @ W0^T-frag
        __syncthreads();   // all LDS reads of GEMM1 done

        stage_w((const float4*)(wt + (size_t)(1 * NW + w) * WMAT_HALVES), (float4*)Wlds, t);
        act_store(Hlds, b_hid + (0 * NW + w) * NEUR, row0, m, q, acc);   // h2
        __syncthreads();

        gemm_tile(Hlds, Wlds, row0, m, q, acc);          // z3 = h2 @ W1^T-frag

        // register epilogue: h3 = tanh(z3 + b); out_p = h3 . W_out ; butterfly over m-lanes
        const float* bh1 = b_hid + (1 * NW + w) * NEUR;
        float t0 = 0.f, t1 = 0.f, t2 = 0.f, t3 = 0.f;
#pragma unroll
        for (int c = 0; c < 8; ++c) {
            float b  = bh1[c * 16 + m];
            float wo = wouts[c * 16 + m];
            t0 = fmaf(tanh_fast(acc[c][0] + b), wo, t0);
            t1 = fmaf(tanh_fast(acc[c][1] + b), wo, t1);
            t2 = fmaf(tanh_fast(acc[c][2] + b), wo, t2);
            t3 = fmaf(tanh_fast(acc[c][3] + b), wo, t3);
        }
#pragma unroll
        for (int d = 1; d <= 8; d <<= 1) {
            t0 += __shfl_xor(t0, d);
            t1 += __shfl_xor(t1, d);
            t2 += __shfl_xor(t2, d);
            t3 += __shfl_xor(t3, d);
        }
        float tot = (rsel == 0) ? t0 : (rsel == 1) ? t1 : (rsel == 2) ? t2 : t3;
        float u   = (tot + b_out[w]) * U_SD + U_MEAN;
        float xv  = xs[row0 + q * 4 + rsel];
        float xl  = (xv - mids[w])     * (1.0f / SIGMA);
        float xr  = (xv - mids[w + 1]) * (1.0f / SIGMA);
        float wf  = __builtin_amdgcn_rcpf(1.0f + __expf(xl)) *
                    __builtin_amdgcn_rcpf(1.0f + __expf(-xr));
        uacc = fmaf(wf, u, uacc);
    }

    if (m < 4) out[blk * TILE + row0 + q * 4 + m] = uacc;
}

extern "C" void kernel_launch(void* const* d_in, const int* in_sizes, int n_in,
                              void* d_out, int out_size, void* d_ws, size_t ws_size,
                              hipStream_t stream) {
    const float* x     = (const float*)d_in[0];
    const float* means = (const float*)d_in[1];
    const float* stds  = (const float*)d_in[2];
    const float* mids  = (const float*)d_in[3];
    const float* W_in  = (const float*)d_in[4];
    const float* b_in  = (const float*)d_in[5];
    const float* W_hid = (const float*)d_in[6];
    const float* b_hid = (const float*)d_in[7];
    const float* W_out = (const float*)d_in[8];
    const float* b_out = (const float*)d_in[9];
    float* out = (float*)d_out;
    _Float16* wt = (_Float16*)d_ws;    // needs 1,081,344 B of scratch

    prep_kernel<<<WT_TOTAL / 256, 256, 0, stream>>>(W_hid, wt);
    fbpinn_kernel<<<NPTS / TILE, NTHR, 0, stream>>>(
        x, means, stds, mids, W_in, b_in, b_hid, W_out, b_out, wt, out);
}

// Round 3
// 258.403 us; speedup vs baseline: 2.6113x; 2.6113x over previous
//
#include <hip/hip_runtime.h>

#define NW    16
#define NEUR  128
#define NPTS  65536
#define SIGMA 0.02f
#define U_MEAN 0.0f
#define U_SD   1.0f

#define TILE   128          // points per block
#define NTHR   512          // 8 waves
#define HPAD   136          // row stride in halves: 272B = 17*16 -> KEEP 16B ALIGNMENT (R2's 132 caused HW replay of misaligned b128)
#define WMAT_HALVES (NEUR*HPAD)           // 17408 halves = 34816 B per weight matrix (2176 float4)
#define WT_TOTAL (2*NW*WMAT_HALVES)       // 557056 halves = 1,114,112 B in d_ws

typedef _Float16 half8 __attribute__((ext_vector_type(8)));
typedef float    f32x4 __attribute__((ext_vector_type(4)));

__device__ __forceinline__ float tanh_fast(float x) {
    // tanh(x) = 1 - 2/(1+exp(2x)); exp->inf / ->0 saturate correctly to +-1
    float e = __expf(2.0f * x);
    return 1.0f - 2.0f * __builtin_amdgcn_rcpf(1.0f + e);
}

// W_hid fp32 [l][w][d][e]  ->  wt fp16 [(l*NW+w)][e][HPAD]  (transposed: k=d contiguous, padded)
__global__ void prep_kernel(const float* __restrict__ W_hid, _Float16* __restrict__ wt) {
    int idx  = blockIdx.x * 256 + threadIdx.x;     // grid sized exactly: 2176*256 = 557056
    int d    = idx % HPAD;
    int rest = idx / HPAD;
    int e    = rest & (NEUR - 1);
    int lw   = rest >> 7;
    _Float16 v = (_Float16)0.0f;
    if (d < NEUR) v = (_Float16)W_hid[(lw * NEUR + d) * NEUR + e];
    wt[idx] = v;
}

// acc[c] = 16x16 tile c of Hlds[128rows x 128k] @ Wlds[128n x 128k]^T
__device__ __forceinline__ void gemm_tile(const _Float16* Hbase, const _Float16* Wbase,
                                          int row0, int m, int q, f32x4 acc[8]) {
    const f32x4 z = {0.f, 0.f, 0.f, 0.f};
#pragma unroll
    for (int c = 0; c < 8; ++c) acc[c] = z;
#pragma unroll
    for (int s = 0; s < 4; ++s) {
        half8 a = *(const half8*)(Hbase + (row0 + m) * HPAD + s * 32 + q * 8);
#pragma unroll
        for (int c = 0; c < 8; ++c) {
            half8 b = *(const half8*)(Wbase + (c * 16 + m) * HPAD + s * 32 + q * 8);
            acc[c] = __builtin_amdgcn_mfma_f32_16x16x32_f16(a, b, acc[c], 0, 0, 0);
        }
    }
}

__device__ __forceinline__ void act_store(_Float16* Hbase, const float* __restrict__ bias,
                                          int row0, int m, int q, const f32x4 acc[8]) {
#pragma unroll
    for (int c = 0; c < 8; ++c) {
        float b = bias[c * 16 + m];
#pragma unroll
        for (int r = 0; r < 4; ++r) {
            // C/D layout: col = lane&15 (=m), row = q*4 + r
            Hbase[(row0 + q * 4 + r) * HPAD + c * 16 + m] = (_Float16)tanh_fast(acc[c][r] + b);
        }
    }
}

__device__ __forceinline__ void stage_w(const float4* __restrict__ g, float4* l4, int t) {
    // 2176 float4 per matrix: 4 per thread + 128-thread tail
    float4 r0 = g[t], r1 = g[t + 512], r2 = g[t + 1024], r3 = g[t + 1536];
    float4 r4;
    if (t < 128) r4 = g[t + 2048];
    l4[t] = r0; l4[t + 512] = r1; l4[t + 1024] = r2; l4[t + 1536] = r3;
    if (t < 128) l4[t + 2048] = r4;
}

__global__ __launch_bounds__(NTHR, 4) void fbpinn_kernel(
    const float* __restrict__ x,     const float* __restrict__ means,
    const float* __restrict__ stds,  const float* __restrict__ mids,
    const float* __restrict__ W_in,  const float* __restrict__ b_in,
    const float* __restrict__ b_hid, const float* __restrict__ W_out,
    const float* __restrict__ b_out, const _Float16* __restrict__ wt,
    float* __restrict__ out)
{
    __shared__ __align__(16) _Float16 Wlds[WMAT_HALVES];   // 34816 B
    __shared__ __align__(16) _Float16 Hlds[TILE * HPAD];   // 34816 B
    __shared__ float xs[TILE];
    __shared__ float wouts[NEUR];

    const int t    = threadIdx.x;
    const int blk  = blockIdx.x;
    const int lane = t & 63;
    const int wave = t >> 6;
    const int m    = lane & 15;        // MFMA col / A-row lane index
    const int q    = lane >> 4;        // MFMA quad
    const int row0 = wave * 16;        // this wave's 16-point slab
    const int p    = t & 127;          // point owned in L0 phase
    const int qq   = t >> 7;           // neuron quarter in L0 phase

    if (t < TILE) xs[t] = x[blk * TILE + t];
    const int rsel = m & 3;
    float uacc = 0.f;
    f32x4 acc[8];

    for (int w = 0; w < NW; ++w) {
        __syncthreads();   // Hlds/Wlds/wouts free (prev window's GEMM2 + epilogue done)

        // stage W(layer0) + W_out; compute layer 0 (1->128) in fp32, b128 stores
        stage_w((const float4*)(wt + (size_t)(0 * NW + w) * WMAT_HALVES), (float4*)Wlds, t);
        if (t < NEUR) wouts[t] = W_out[w * NEUR + t];

        const float xn = (xs[p] - means[w]) * __builtin_amdgcn_rcpf(stds[w]);
        const float* win = W_in + w * NEUR;
        const float* bin = b_in + w * NEUR;
#pragma unroll
        for (int i8 = 0; i8 < 4; ++i8) {
            const int n0 = qq * 32 + i8 * 8;
            float4 wv0 = *(const float4*)&win[n0];
            float4 wv1 = *(const float4*)&win[n0 + 4];
            float4 bv0 = *(const float4*)&bin[n0];
            float4 bv1 = *(const float4*)&bin[n0 + 4];
            half8 hv;
            hv[0] = (_Float16)tanh_fast(fmaf(xn, wv0.x, bv0.x));
            hv[1] = (_Float16)tanh_fast(fmaf(xn, wv0.y, bv0.y));
            hv[2] = (_Float16)tanh_fast(fmaf(xn, wv0.z, bv0.z));
            hv[3] = (_Float16)tanh_fast(fmaf(xn, wv0.w, bv0.w));
            hv[4] = (_Float16)tanh_fast(fmaf(xn, wv1.x, bv1.x));
            hv[5] = (_Float16)tanh_fast(fmaf(xn, wv1.y, bv1.y));
            hv[6] = (_Float16)tanh_fast(fmaf(xn, wv1.z, bv1.z));
            hv[7] = (_Float16)tanh_fast(fmaf(xn, wv1.w, bv1.w));
            *(half8*)&Hlds[p * HPAD + n0] = hv;
        }
        __syncthreads();   // h1, W0, wouts visible

        gemm_tile(Hlds, Wlds, row0, m, q, acc);          // z2 = h1 @ W0^T-frag
        __syncthreads();   // all LDS reads of GEMM1 done

        stage_w((const float4*)(wt + (size_t)(1 * NW + w) * WMAT_HALVES), (float4*)Wlds, t);
        act_store(Hlds, b_hid + (0 * NW + w) * NEUR, row0, m, q, acc);   // h2
        __syncthreads();

        gemm_tile(Hlds, Wlds, row0, m, q, acc);          // z3 = h2 @ W1^T-frag

        // register epilogue: h3 = tanh(z3 + b); out_p = h3 . W_out ; reduce over 16 m-lanes
        const float* bh1 = b_hid + (1 * NW + w) * NEUR;
        float t0 = 0.f, t1 = 0.f, t2 = 0.f, t3 = 0.f;
#pragma unroll
        for (int c = 0; c < 8; ++c) {
            float b  = bh1[c * 16 + m];
            float wo = wouts[c * 16 + m];
            t0 = fmaf(tanh_fast(acc[c][0] + b), wo, t0);
            t1 = fmaf(tanh_fast(acc[c][1] + b), wo, t1);
            t2 = fmaf(tanh_fast(acc[c][2] + b), wo, t2);
            t3 = fmaf(tanh_fast(acc[c][3] + b), wo, t3);
        }
        // 2 butterfly stages on all four partials, select, then 2 more stages
        t0 += __shfl_xor(t0, 1); t1 += __shfl_xor(t1, 1);
        t2 += __shfl_xor(t2, 1); t3 += __shfl_xor(t3, 1);
        t0 += __shfl_xor(t0, 2); t1 += __shfl_xor(t1, 2);
        t2 += __shfl_xor(t2, 2); t3 += __shfl_xor(t3, 2);
        float v = (rsel == 0) ? t0 : (rsel == 1) ? t1 : (rsel == 2) ? t2 : t3;
        v += __shfl_xor(v, 4);
        v += __shfl_xor(v, 8);

        float u   = (v + b_out[w]) * U_SD + U_MEAN;
        float xv  = xs[row0 + q * 4 + rsel];
        float xl  = (xv - mids[w])     * (1.0f / SIGMA);
        float xr  = (xv - mids[w + 1]) * (1.0f / SIGMA);
        float wf  = __builtin_amdgcn_rcpf(1.0f + __expf(xl)) *
                    __builtin_amdgcn_rcpf(1.0f + __expf(-xr));
        uacc = fmaf(wf, u, uacc);
    }

    if (m < 4) out[blk * TILE + row0 + q * 4 + m] = uacc;
}

extern "C" void kernel_launch(void* const* d_in, const int* in_sizes, int n_in,
                              void* d_out, int out_size, void* d_ws, size_t ws_size,
                              hipStream_t stream) {
    const float* x     = (const float*)d_in[0];
    const float* means = (const float*)d_in[1];
    const float* stds  = (const float*)d_in[2];
    const float* mids  = (const float*)d_in[3];
    const float* W_in  = (const float*)d_in[4];
    const float* b_in  = (const float*)d_in[5];
    const float* W_hid = (const float*)d_in[6];
    const float* b_hid = (const float*)d_in[7];
    const float* W_out = (const float*)d_in[8];
    const float* b_out = (const float*)d_in[9];
    float* out = (float*)d_out;
    _Float16* wt = (_Float16*)d_ws;    // needs 1,114,112 B of scratch

    prep_kernel<<<WT_TOTAL / 256, 256, 0, stream>>>(W_hid, wt);
    fbpinn_kernel<<<NPTS / TILE, NTHR, 0, stream>>>(
        x, means, stds, mids, W_in, b_in, b_hid, W_out, b_out, wt, out);
}